// Round 14
// baseline (549.499 us; speedup 1.0000x reference)
//
#include <hip/hip_runtime.h>
#include <math.h>

// ---------------------------------------------------------------------------
// VQ-VAE forward, round 13.
// vs round 12 (542us): (1) LDS swizzle upgraded to s^((s>>3)&7)^((s>>8)&7) —
// deconv2/conv3 A-reads stride 256 slots per lane (bits>=8), which the old
// s^((s>>3)&7) could not fold into banks -> 2x imbalance (measured: exactly
// 4 conflict-cycles/read). Stage-side permutation lane^((lane>>3)&7)^((u>>2)&7)
// keeps the involution chunk-local. (2) deconv3: 2 output rows per block
// (stage 4 d2 rows serving 2 rows; 4096 blocks, 4 blocks/CU).
// MFMA 16x16x32 layouts (m89): A/B frag row=lane&15, k=(lane>>4)*8+j.
// C/D: col=lane&15, row=(lane>>4)*4+reg.
// ---------------------------------------------------------------------------

typedef __attribute__((ext_vector_type(8))) short bf16x8;
typedef __attribute__((ext_vector_type(4))) float fx4;
typedef unsigned short ushort_t;
#define MFMA16(a, b, c) __builtin_amdgcn_mfma_f32_16x16x32_bf16(a, b, c, 0, 0, 0)

__device__ inline ushort_t f2bf(float f) {
    unsigned u = __float_as_uint(f);
    u += 0x7FFFu + ((u >> 16) & 1u);
    return (ushort_t)(u >> 16);
}
__device__ inline float bf2f(ushort_t h) {
    return __uint_as_float(((unsigned)h) << 16);
}

__device__ __forceinline__ void stage16(const ushort_t* g, ushort_t* l) {
#if __has_builtin(__builtin_amdgcn_global_load_lds)
    __builtin_amdgcn_global_load_lds(
        (const __attribute__((address_space(1))) unsigned int*)g,
        (__attribute__((address_space(3))) unsigned int*)l, 16, 0, 0);
#else
    int lane = threadIdx.x & 63;
    *(int4*)(l + lane * 8) = *(const int4*)g;
#endif
}

// swizzle over 16B slots (involution): folds bits 3-5 AND bit 8+ into banks.
__device__ __forceinline__ int swz(int s) {
    return s ^ ((s >> 3) & 7) ^ ((s >> 8) & 7);
}
// stage-side source permutation for chunk u (64 slots): consistent with swz.
__device__ __forceinline__ int ssl(int lane, int u) {
    return lane ^ ((lane >> 3) & 7) ^ ((u >> 2) & 7);
}
__device__ __forceinline__ bf16x8 sld(const ushort_t* sm, int gslot) {
    return *(const bf16x8*)(sm + (size_t)swz(gslot) * 8);
}

__device__ __forceinline__ void halo_do(
    ushort_t* __restrict__ buf, int B, int H, int W, int C8, int idx)
{
    int perim = 2 * W + 2 * (H - 2);
    int c8 = idx % C8;
    int t = idx / C8;
    int p = t % perim;
    int b = t / perim;
    int r, col;
    if (p < W) { r = 0; col = p; }
    else if (p < 2 * W) { r = H - 1; col = p - W; }
    else { int pp = p - 2 * W; r = 1 + (pp >> 1); col = (pp & 1) ? (W - 1) : 0; }
    size_t off = ((((size_t)b * H + r) * W + col) * C8 + c8) * 8;
    *(int4*)(buf + off) = (int4){0, 0, 0, 0};
}

__global__ __launch_bounds__(256) void halo3_k(
    ushort_t* __restrict__ xp, ushort_t* __restrict__ h2p, ushort_t* __restrict__ qpad)
{
    int i = blockIdx.x * 256 + threadIdx.x;
    if (i < 132096) halo_do(xp, 32, 130, 130, 8, i);
    else if (i < 265216) halo_do(h2p, 32, 66, 66, 16, i - 132096);
    else if (i < 331776) halo_do(qpad, 32, 66, 66, 8, i - 265216);
}
__global__ __launch_bounds__(256) void halo2_k(
    ushort_t* __restrict__ d1c, ushort_t* __restrict__ d2c)
{
    int i = blockIdx.x * 256 + threadIdx.x;
    if (i < 132096) halo_do(d1c, 16, 130, 130, 16, i);
    else if (i < 263680) halo_do(d2c, 16, 258, 258, 8, i - 132096);
}

// x (32,3,256,256) f32 -> x4 [32][258][258][4] bf16 (ci=3 zero); + halo zero
__global__ __launch_bounds__(256) void cast_x4(
    const float* __restrict__ x, ushort_t* __restrict__ x4)
{
    if (blockIdx.x < 8192) {
        int i = blockIdx.x * 256 + threadIdx.x;
        int w = i & 255, h = (i >> 8) & 255, b = i >> 16;
        size_t base = ((size_t)b * 3 * 256 + h) * 256 + w;
        float v0 = x[base];
        float v1 = x[base + 65536];
        float v2 = x[base + 131072];
        uint2 o;
        o.x = (unsigned)f2bf(v0) | ((unsigned)f2bf(v1) << 16);
        o.y = (unsigned)f2bf(v2);
        *(uint2*)(x4 + ((size_t)(b * 258 + h + 1) * 258 + (w + 1)) * 4) = o;
    } else {
        int idx = (blockIdx.x - 8192) * 256 + threadIdx.x;
        if (idx >= 32 * 1032) return;
        int b = idx / 1032;
        int s = idx % 1032;
        int side = s / 258, c = s % 258;
        int r, col;
        if (side == 0) { r = 0; col = c; }
        else if (side == 1) { r = 257; col = c; }
        else if (side == 2) { r = c; col = 0; }
        else { r = c; col = 257; }
        *(uint2*)(x4 + ((size_t)(b * 258 + r) * 258 + col) * 4) = (uint2){0, 0};
    }
}

// ---------------- fused repack: all weights + embb + se2 + lac --------------
// 16-wide swizzled layout: off = ((t*numC + c)*64 + lane)*8 + j ;
// co = t*16 + (lane&15); k = c*32 + (lane>>4)*8 + j
__global__ __launch_bounds__(256) void repack_all(
    const float* __restrict__ w1, const float* __restrict__ w2,
    const float* __restrict__ w3, const float* __restrict__ dw1,
    const float* __restrict__ dw2, const float* __restrict__ dw3,
    const float* __restrict__ emb,
    ushort_t* __restrict__ o1, ushort_t* __restrict__ o2,
    ushort_t* __restrict__ o3, ushort_t* __restrict__ od1,
    ushort_t* __restrict__ od2, ushort_t* __restrict__ od3,
    ushort_t* __restrict__ embb, float* __restrict__ se2,
    float* __restrict__ lac)
{
    int gi = blockIdx.x * 256 + threadIdx.x;
    if (gi < 4096) {                         // w1 [64co][3ci][4][4]
        int i = gi;
        int j = i & 7, lane = (i >> 3) & 63, tc = i >> 9;
        int c = tc & 1, t = tc >> 1;
        int co = t * 16 + (lane & 15);
        int k = c * 32 + (lane >> 4) * 8 + j;
        int kh = k >> 4, kw = (k >> 2) & 3, ci = k & 3;
        o1[i] = (ci < 3) ? f2bf(w1[((co * 3 + ci) * 4 + kh) * 4 + kw]) : (ushort_t)0;
    } else if (gi < 135168) {                // w2 [128co][64ci][4][4], numC=32
        int i = gi - 4096;
        int j = i & 7, lane = (i >> 3) & 63, tc = i >> 9;
        int c = tc & 31, t = tc >> 5;
        int co = t * 16 + (lane & 15);
        int k = c * 32 + (lane >> 4) * 8 + j;
        int tap = k >> 6, ci = k & 63, kh = tap >> 2, kw = tap & 3;
        o2[i] = f2bf(w2[((co * 64 + ci) * 4 + kh) * 4 + kw]);
    } else if (gi < 208896) {                // w3 [64co][128ci][3][3], numC=36
        int i = gi - 135168;
        int j = i & 7, lane = (i >> 3) & 63, tc = i >> 9;
        int c = tc % 36, t = tc / 36;
        int co = t * 16 + (lane & 15);
        int k = c * 32 + (lane >> 4) * 8 + j;
        int tap = k >> 7, ci = k & 127, kh = tap / 3, kw = tap % 3;
        o3[i] = f2bf(w3[((co * 128 + ci) * 3 + kh) * 3 + kw]);
    } else if (gi < 339968) {                // dw1 [64ci][128co][4][4], numC=32
        int i = gi - 208896;
        int j = i & 7, lane = (i >> 3) & 63, tc = i >> 9;
        int c = tc & 31, t = tc >> 5;
        int co = t * 16 + (lane & 15);
        int k = c * 32 + (lane >> 4) * 8 + j;
        int tap = k >> 6, ci = k & 63, kh = tap >> 2, kw = tap & 3;
        od1[i] = f2bf(dw1[((ci * 128 + co) * 4 + kh) * 4 + kw]);
    } else if (gi < 471040) {                // dw2 [128ci][64co][4][4], numC=64
        int i = gi - 339968;
        int j = i & 7, lane = (i >> 3) & 63, tc = i >> 9;
        int c = tc & 63, t = tc >> 6;
        int co = t * 16 + (lane & 15);
        int k = c * 32 + (lane >> 4) * 8 + j;
        int tap = k >> 7, ci = k & 127, kh = tap >> 2, kw = tap & 3;
        od2[i] = f2bf(dw2[((ci * 64 + co) * 4 + kh) * 4 + kw]);
    } else if (gi < 480256) {                // dw3 [64ci][3co][3][3], numC=18
        int i = gi - 471040;
        int j = i & 7, lane = (i >> 3) & 63, c = i >> 9;
        int co = lane & 15;
        int k = c * 32 + (lane >> 4) * 8 + j;
        int tap = k >> 6, ci = k & 63, kh = tap / 3, kw = tap % 3;
        od3[i] = (co < 3) ? f2bf(dw3[((ci * 3 + co) * 3 + kh) * 3 + kw]) : (ushort_t)0;
    } else if (gi < 513024) {                // embb [512n][64k] B-frag layout
        int i = gi - 480256;
        int j = i & 7, lane = (i >> 3) & 63, c = (i >> 9) & 1, nt = i >> 10;
        int n = nt * 16 + (lane & 15);
        int k = c * 32 + (lane >> 4) * 8 + j;
        embb[i] = f2bf(emb[n * 64 + k]);
    } else if (gi < 513536) {                // se2[512] fp32 |e|^2
        int n = gi - 513024;
        const float* e = emb + n * 64;
        float s = 0.f;
        for (int d = 0; d < 64; ++d) s = fmaf(e[d], e[d], s);
        se2[n] = s;
    } else if (gi == 513536) {
        lac[0] = 0.f;
    }
}

// ------------------------- conv1 MFMA ---------------------------------------
// grid 4096 = 8 xcd x (32 b x 16 ohi); oh = xcd*16 + ohi
__global__ __launch_bounds__(256) void conv1_mfma(
    const ushort_t* __restrict__ x4, const ushort_t* __restrict__ wr,
    const float* __restrict__ bias, ushort_t* __restrict__ xp)
{
    __shared__ ushort_t sm[4608];
    int tid = threadIdx.x;
    int wv = tid >> 6, lane = tid & 63;
    int n16 = lane & 15, quad = lane >> 4;
    int i = blockIdx.x;
    int xcd = i & 7, j = i >> 3;
    int b = j >> 4, oh = xcd * 16 + (j & 15);
    const ushort_t* gsrc = x4 + (size_t)(b * 258 + 2 * oh) * 1032;
    bf16x8 bfr[4][2];
    #pragma unroll
    for (int nt = 0; nt < 4; ++nt)
        #pragma unroll
        for (int c = 0; c < 2; ++c)
            bfr[nt][c] = *(const bf16x8*)(wr + ((size_t)(nt * 2 + c) * 64 + lane) * 8);
    for (int u = wv; u < 9; u += 4)
        stage16(gsrc + u * 512 + ssl(lane, u) * 8, sm + u * 512);
    __syncthreads();

    fx4 acc[2][4];
    #pragma unroll
    for (int i2 = 0; i2 < 2; ++i2)
        #pragma unroll
        for (int j2 = 0; j2 < 4; ++j2) acc[i2][j2] = (fx4){0.f, 0.f, 0.f, 0.f};
    #pragma unroll
    for (int c = 0; c < 2; ++c) {
        int kh = 2 * c + (quad >> 1);
        int kwh = quad & 1;
        bf16x8 af[2];
        #pragma unroll
        for (int mt = 0; mt < 2; ++mt) {
            int ow = (wv * 2 + mt) * 16 + n16;
            af[mt] = sld(sm, kh * 129 + ow + kwh);
        }
        #pragma unroll
        for (int mt = 0; mt < 2; ++mt)
            #pragma unroll
            for (int nt = 0; nt < 4; ++nt)
                acc[mt][nt] = MFMA16(af[mt], bfr[nt][c], acc[mt][nt]);
    }
    #pragma unroll
    for (int nt = 0; nt < 4; ++nt) {
        int co = nt * 16 + n16;
        float bs = bias[co];
        #pragma unroll
        for (int mt = 0; mt < 2; ++mt) {
            #pragma unroll
            for (int r = 0; r < 4; ++r) {
                int ow = (wv * 2 + mt) * 16 + quad * 4 + r;
                xp[((size_t)(b * 130 + oh + 1) * 130 + (ow + 1)) * 64 + co] =
                    f2bf(fmaxf(acc[mt][nt][r] + bs, 0.f));
            }
        }
    }
}

// ------------------------- conv2 MFMA ---------------------------------------
// grid 2048 = 8 xcd x (32 b x 8 ohi); oh = xcd*8 + ohi
__global__ __launch_bounds__(256, 2) void conv2_mfma(
    const ushort_t* __restrict__ xp, const ushort_t* __restrict__ wr,
    const float* __restrict__ bias, ushort_t* __restrict__ h2p)
{
    __shared__ ushort_t sm[33280];
    int tid = threadIdx.x;
    int wv = tid >> 6, lane = tid & 63;
    int n16 = lane & 15, quad = lane >> 4;
    int i = blockIdx.x;
    int xcd = i & 7, j = i >> 3;
    int b = j >> 3, oh = xcd * 8 + (j & 7);
    const ushort_t* gsrc = xp + (size_t)(b * 130 + 2 * oh) * 130 * 64;
    int mg = wv & 1, ng = wv >> 1;

    bf16x8 Bb[8];
    #pragma unroll
    for (int nt = 0; nt < 4; ++nt)
        #pragma unroll
        for (int ks = 0; ks < 2; ++ks)
            Bb[nt * 2 + ks] = *(const bf16x8*)(
                wr + ((size_t)((ng * 4 + nt) * 32 + 0 * 2 + ks) * 64 + lane) * 8);
    for (int u = wv; u < 65; u += 4)
        stage16(gsrc + (size_t)u * 512 + ssl(lane, u) * 8, sm + u * 512);
    __syncthreads();

    fx4 acc[2][4];
    #pragma unroll
    for (int i2 = 0; i2 < 2; ++i2)
        #pragma unroll
        for (int j2 = 0; j2 < 4; ++j2) acc[i2][j2] = (fx4){0.f, 0.f, 0.f, 0.f};
    for (int tap = 0; tap < 16; ++tap) {
        if (tap > 0) {
            #pragma unroll
            for (int nt = 0; nt < 4; ++nt)
                #pragma unroll
                for (int ks = 0; ks < 2; ++ks)
                    Bb[nt * 2 + ks] = *(const bf16x8*)(
                        wr + ((size_t)((ng * 4 + nt) * 32 + tap * 2 + ks) * 64 + lane) * 8);
        }
        int kh = tap >> 2, kw = tap & 3;
        #pragma unroll
        for (int ks = 0; ks < 2; ++ks) {
            bf16x8 af[2];
            #pragma unroll
            for (int mt = 0; mt < 2; ++mt) {
                int px = kw + 2 * ((mg * 2 + mt) * 16 + n16);   // 0..129
                af[mt] = sld(sm, (kh * 130 + px) * 8 + ks * 4 + quad);
            }
            #pragma unroll
            for (int mt = 0; mt < 2; ++mt)
                #pragma unroll
                for (int nt = 0; nt < 4; ++nt)
                    acc[mt][nt] = MFMA16(af[mt], Bb[nt * 2 + ks], acc[mt][nt]);
        }
    }
    #pragma unroll
    for (int nt = 0; nt < 4; ++nt) {
        int co = (ng * 4 + nt) * 16 + n16;
        float bs = bias[co];
        #pragma unroll
        for (int mt = 0; mt < 2; ++mt) {
            #pragma unroll
            for (int r = 0; r < 4; ++r) {
                int ow = (mg * 2 + mt) * 16 + quad * 4 + r;
                h2p[((size_t)(b * 66 + oh + 1) * 66 + (ow + 1)) * 128 + co] =
                    f2bf(fmaxf(acc[mt][nt][r] + bs, 0.f));
            }
        }
    }
}

// ------------------------- conv3 MFMA ---------------------------------------
// grid 2048 = 8 xcd x (32 b x 8 ohi); oh = xcd*8 + ohi
__global__ __launch_bounds__(256, 2) void conv3_mfma(
    const ushort_t* __restrict__ hp, const ushort_t* __restrict__ wr,
    const float* __restrict__ bias, ushort_t* __restrict__ z)
{
    __shared__ ushort_t sm[25600];
    int tid = threadIdx.x;
    int wv = tid >> 6, lane = tid & 63;
    int n16 = lane & 15, quad = lane >> 4;
    int i = blockIdx.x;
    int xcd = i & 7, j = i >> 3;
    int b = j >> 3, oh = xcd * 8 + (j & 7);
    const ushort_t* gsrc = hp + (size_t)(b * 66 + oh) * 66 * 128;
    const ushort_t* wb = wr + ((size_t)wv * 36 * 64 + lane) * 8;
    bf16x8 Bb[36];
    #pragma unroll
    for (int s = 0; s < 36; ++s)
        Bb[s] = *(const bf16x8*)(wb + (size_t)s * 512);
    for (int u = wv; u < 50; u += 4)
        stage16(gsrc + (size_t)u * 512 + ssl(lane, u) * 8, sm + u * 512);
    __syncthreads();

    fx4 acc[4];
    #pragma unroll
    for (int i2 = 0; i2 < 4; ++i2) acc[i2] = (fx4){0.f, 0.f, 0.f, 0.f};
    #pragma unroll
    for (int tap = 0; tap < 9; ++tap) {
        int kh = tap / 3, kw = tap % 3;
        #pragma unroll
        for (int ks = 0; ks < 4; ++ks) {
            bf16x8 af[4];
            #pragma unroll
            for (int mt = 0; mt < 4; ++mt) {
                int px = kw + mt * 16 + n16;                    // 0..65
                af[mt] = sld(sm, (kh * 66 + px) * 16 + ks * 4 + quad);
            }
            #pragma unroll
            for (int mt = 0; mt < 4; ++mt)
                acc[mt] = MFMA16(af[mt], Bb[tap * 4 + ks], acc[mt]);
        }
    }
    int co = wv * 16 + n16;
    float bs = bias[co];
    #pragma unroll
    for (int mt = 0; mt < 4; ++mt) {
        #pragma unroll
        for (int r = 0; r < 4; ++r) {
            int ow = mt * 16 + quad * 4 + r;
            z[((size_t)(b * 64 + oh) * 64 + ow) * 64 + co] =
                f2bf(fmaxf(acc[mt][r] + bs, 0.f));
        }
    }
}

// ------------------------- VQ MFMA ------------------------------------------
__global__ __launch_bounds__(256) void vq_mfma(
    const ushort_t* __restrict__ z, const ushort_t* __restrict__ embb,
    const float* __restrict__ emb, const float* __restrict__ se2g,
    ushort_t* __restrict__ qpad, float* __restrict__ loss_acc)
{
    __shared__ ushort_t smz[16384];
    __shared__ float sse2[512];
    __shared__ float red[256];
    int tid = threadIdx.x;
    int wv = tid >> 6, lane = tid & 63;
    int n16 = lane & 15, quad = lane >> 4;
    int blk = blockIdx.x;                   // 512
    const ushort_t* gsrc = z + (size_t)blk * 16384;
    for (int u = wv; u < 32; u += 4)
        stage16(gsrc + (size_t)u * 512 + ssl(lane, u) * 8, smz + u * 512);
    for (int i = tid; i < 512; i += 256) sse2[i] = se2g[i];
    __syncthreads();

    bf16x8 a[4][2];
    #pragma unroll
    for (int mt = 0; mt < 4; ++mt)
        #pragma unroll
        for (int ks = 0; ks < 2; ++ks)
            a[mt][ks] = sld(smz, (wv * 64 + mt * 16 + n16) * 8 + ks * 4 + quad);

    float best[4][4];
    int bid[4][4];
    #pragma unroll
    for (int mt = 0; mt < 4; ++mt)
        #pragma unroll
        for (int r = 0; r < 4; ++r) { best[mt][r] = 1e30f; bid[mt][r] = 0; }

    for (int nt = 0; nt < 32; ++nt) {
        bf16x8 b0 = *(const bf16x8*)(embb + ((size_t)(nt * 2 + 0) * 64 + lane) * 8);
        bf16x8 b1 = *(const bf16x8*)(embb + ((size_t)(nt * 2 + 1) * 64 + lane) * 8);
        float s2 = sse2[nt * 16 + n16];
        int myn = nt * 16 + n16;
        #pragma unroll
        for (int mt = 0; mt < 4; ++mt) {
            fx4 acc = (fx4){0.f, 0.f, 0.f, 0.f};
            acc = MFMA16(a[mt][0], b0, acc);
            acc = MFMA16(a[mt][1], b1, acc);
            #pragma unroll
            for (int r = 0; r < 4; ++r) {
                float sc = fmaf(-2.f, acc[r], s2);
                if (sc < best[mt][r]) { best[mt][r] = sc; bid[mt][r] = myn; }
            }
        }
    }

    float lsum = 0.f;
    #pragma unroll
    for (int mt = 0; mt < 4; ++mt) {
        #pragma unroll
        for (int r = 0; r < 4; ++r) {
            float bs = best[mt][r];
            int bi = bid[mt][r];
            #pragma unroll
            for (int st = 1; st < 16; st <<= 1) {
                float os = __shfl_xor(bs, st, 64);
                int oi = __shfl_xor(bi, st, 64);
                if (os < bs || (os == bs && oi < bi)) { bs = os; bi = oi; }
            }
            int ml = wv * 64 + mt * 16 + quad * 4 + r;
            int pos = blk * 256 + ml;
            int b = pos >> 12, h = (pos >> 6) & 63, w = pos & 63;
            float4 ev = *(const float4*)(emb + (size_t)bi * 64 + n16 * 4);
            int slot = ml * 8 + (n16 >> 1);
            const ushort_t* zp = smz + (size_t)swz(slot) * 8 + (n16 & 1) * 4;
            float d0 = ev.x - bf2f(zp[0]);
            float d1 = ev.y - bf2f(zp[1]);
            float d2 = ev.z - bf2f(zp[2]);
            float d3 = ev.w - bf2f(zp[3]);
            lsum = fmaf(d0, d0, lsum);
            lsum = fmaf(d1, d1, lsum);
            lsum = fmaf(d2, d2, lsum);
            lsum = fmaf(d3, d3, lsum);
            uint2 o;
            o.x = (unsigned)f2bf(ev.x) | ((unsigned)f2bf(ev.y) << 16);
            o.y = (unsigned)f2bf(ev.z) | ((unsigned)f2bf(ev.w) << 16);
            *(uint2*)(qpad + ((size_t)(b * 66 + h + 1) * 66 + (w + 1)) * 64 + n16 * 4) = o;
        }
    }
    red[tid] = lsum;
    __syncthreads();
    for (int s = 128; s > 0; s >>= 1) {
        if (tid < s) red[tid] += red[tid + s];
        __syncthreads();
    }
    if (tid == 0) atomicAdd(loss_acc, red[0]);
}

__global__ void loss_fin_k(const float* __restrict__ acc, float* __restrict__ out)
{
    out[0] = 1.25f * acc[0] / 8388608.0f;
}

// ------------------------- deconv1 MFMA -------------------------------------
// grid 2048 = 8 xcd x (16 b x 16 ohi); oh = xcd*16 + ohi
__global__ __launch_bounds__(256, 2) void deconv1_mfma(
    const ushort_t* __restrict__ q, const ushort_t* __restrict__ wr,
    const float* __restrict__ bias, ushort_t* __restrict__ d1)
{
    __shared__ ushort_t sm[8704];
    int tid = threadIdx.x;
    int wv = tid >> 6, lane = tid & 63;
    int n16 = lane & 15, quad = lane >> 4;
    int i = blockIdx.x;
    int xcd = i & 7, j = i >> 3;
    int b = j >> 4, oh = xcd * 16 + (j & 15);
    int h0 = (oh + 1) & 1;
    int ihp0 = ((oh + 1 - h0) >> 1) + 1;
    const ushort_t* gsrc = q + (size_t)(b * 66 + ihp0 - 1) * 66 * 64;
    int pw = wv & 1, ng = wv >> 1;
    int q0 = 1 - pw;
    bf16x8 Bb[4][8];
    #pragma unroll
    for (int nt = 0; nt < 4; ++nt) {
        const ushort_t* wb = wr + ((size_t)(ng * 4 + nt) * 32 * 64 + lane) * 8;
        #pragma unroll
        for (int t2 = 0; t2 < 2; ++t2)
            #pragma unroll
            for (int t3 = 0; t3 < 2; ++t3)
                #pragma unroll
                for (int ks = 0; ks < 2; ++ks) {
                    int tap = (h0 + 2 * t2) * 4 + (q0 + 2 * t3);
                    Bb[nt][t2 * 4 + t3 * 2 + ks] =
                        *(const bf16x8*)(wb + (size_t)(tap * 2 + ks) * 512);
                }
    }
    for (int u = wv; u < 17; u += 4)
        stage16(gsrc + (size_t)u * 512 + ssl(lane, u) * 8, sm + u * 512);
    __syncthreads();

    fx4 acc[4][4];
    #pragma unroll
    for (int i2 = 0; i2 < 4; ++i2)
        #pragma unroll
        for (int j2 = 0; j2 < 4; ++j2) acc[i2][j2] = (fx4){0.f, 0.f, 0.f, 0.f};
    #pragma unroll
    for (int t2 = 0; t2 < 2; ++t2) {
        int lrow = 1 - t2;
        #pragma unroll
        for (int t3 = 0; t3 < 2; ++t3) {
            int cadd = pw + (t3 == 0 ? 1 : 0);
            #pragma unroll
            for (int ks = 0; ks < 2; ++ks) {
                bf16x8 af[4];
                #pragma unroll
                for (int mt = 0; mt < 4; ++mt) {
                    int px = cadd + mt * 16 + n16;              // 0..65
                    af[mt] = sld(sm, (lrow * 66 + px) * 8 + ks * 4 + quad);
                }
                #pragma unroll
                for (int mt = 0; mt < 4; ++mt)
                    #pragma unroll
                    for (int nt = 0; nt < 4; ++nt)
                        acc[mt][nt] = MFMA16(af[mt], Bb[nt][t2 * 4 + t3 * 2 + ks], acc[mt][nt]);
            }
        }
    }
    #pragma unroll
    for (int nt = 0; nt < 4; ++nt) {
        int co = (ng * 4 + nt) * 16 + n16;
        float bs = bias[co];
        #pragma unroll
        for (int mt = 0; mt < 4; ++mt) {
            #pragma unroll
            for (int r = 0; r < 4; ++r) {
                int ow = 2 * (mt * 16 + quad * 4 + r) + pw;
                d1[((size_t)(b * 130 + oh + 1) * 130 + (ow + 1)) * 128 + co] =
                    f2bf(fmaxf(acc[mt][nt][r] + bs, 0.f));
            }
        }
    }
}

// ------------------------- deconv2 MFMA (full-row, 4mt x 4nt) ---------------
// grid 4096 = 8 xcd x (16 b x 32 ohi); oh = xcd*32 + ohi
__global__ __launch_bounds__(256, 2) void deconv2_mfma(
    const ushort_t* __restrict__ d1, const ushort_t* __restrict__ wr,
    const float* __restrict__ bias, ushort_t* __restrict__ d2)
{
    __shared__ ushort_t sm[33280];
    int tid = threadIdx.x;
    int wv = tid >> 6, lane = tid & 63;
    int n16 = lane & 15, quad = lane >> 4;
    int i = blockIdx.x;
    int xcd = i & 7, j = i >> 3;
    int b = j >> 5, oh = xcd * 32 + (j & 31);
    int h0 = (oh + 1) & 1;
    int ihp0 = ((oh + 1 - h0) >> 1) + 1;    // 1..129
    const ushort_t* gsrc = d1 + (size_t)(b * 130 + ihp0 - 1) * 130 * 128;
    int pw = wv & 1, mh = wv >> 1;
    int q0 = 1 - pw;

    int taps[4];
    #pragma unroll
    for (int g = 0; g < 4; ++g)
        taps[g] = (h0 + 2 * (g >> 1)) * 4 + (q0 + 2 * (g & 1));

    bf16x8 Bb[16];
    #pragma unroll
    for (int nt = 0; nt < 4; ++nt)
        #pragma unroll
        for (int ks = 0; ks < 4; ++ks)
            Bb[nt * 4 + ks] = *(const bf16x8*)(
                wr + ((size_t)(nt * 64 + taps[0] * 4 + ks) * 64 + lane) * 8);

    for (int u = wv; u < 65; u += 4)
        stage16(gsrc + (size_t)u * 512 + ssl(lane, u) * 8, sm + u * 512);
    __syncthreads();

    fx4 acc[4][4];
    #pragma unroll
    for (int i2 = 0; i2 < 4; ++i2)
        #pragma unroll
        for (int j2 = 0; j2 < 4; ++j2) acc[i2][j2] = (fx4){0.f, 0.f, 0.f, 0.f};

    #pragma unroll
    for (int g = 0; g < 4; ++g) {
        if (g > 0) {
            int tapc = taps[g];
            #pragma unroll
            for (int nt = 0; nt < 4; ++nt)
                #pragma unroll
                for (int ks = 0; ks < 4; ++ks)
                    Bb[nt * 4 + ks] = *(const bf16x8*)(
                        wr + ((size_t)(nt * 64 + tapc * 4 + ks) * 64 + lane) * 8);
        }
        int t2 = g >> 1, t3 = g & 1;
        int lrow = 1 - t2;
        int cadd = pw + (t3 == 0 ? 1 : 0);
        #pragma unroll
        for (int ks = 0; ks < 4; ++ks) {
            bf16x8 af[4];
            #pragma unroll
            for (int mt = 0; mt < 4; ++mt) {
                int px = cadd + (mh * 4 + mt) * 16 + n16;       // 0..129
                af[mt] = sld(sm, (lrow * 130 + px) * 16 + ks * 4 + quad);
            }
            #pragma unroll
            for (int mt = 0; mt < 4; ++mt)
                #pragma unroll
                for (int nt = 0; nt < 4; ++nt)
                    acc[mt][nt] = MFMA16(af[mt], Bb[nt * 4 + ks], acc[mt][nt]);
        }
    }

    #pragma unroll
    for (int nt = 0; nt < 4; ++nt) {
        int co = nt * 16 + n16;
        float bs = bias[co];
        #pragma unroll
        for (int mt = 0; mt < 4; ++mt) {
            #pragma unroll
            for (int r = 0; r < 4; ++r) {
                int t = (mh * 4 + mt) * 16 + quad * 4 + r;      // 0..127
                int ow = 2 * t + pw;
                d2[((size_t)(b * 258 + oh + 1) * 258 + (ow + 1)) * 64 + co] =
                    f2bf(fmaxf(acc[mt][nt][r] + bs, 0.f));
            }
        }
    }
}

// ------------------------- deconv3 MFMA (2 rows/block) ----------------------
// grid 4096 = 8 xcd x (16 b x 2 half x 16 ohpi); oh0 = (xcd*16+ohpi)*2.
// Stage 4 d2 rows x 136px (68 chunks, 34.8KB -> 4 blocks/CU); wave=(rr,mg):
// output row oh0+rr, 4mt.
__global__ __launch_bounds__(256, 4) void deconv3_mfma(
    const ushort_t* __restrict__ d2, const ushort_t* __restrict__ wr,
    const float* __restrict__ bias, float* __restrict__ out)
{
    __shared__ ushort_t sm[34816];
    int tid = threadIdx.x;
    int wv = tid >> 6, lane = tid & 63;
    int n16 = lane & 15, quad = lane >> 4;
    int i = blockIdx.x;
    int xcd = i & 7, j = i >> 3;            // j 0..511
    int bh = j >> 4;                        // 0..31
    int b = bh >> 1, half = bh & 1;
    int oh0 = (xcd * 16 + (j & 15)) * 2;    // 0,2,..,254
    bf16x8 Bb[18];
    #pragma unroll
    for (int s = 0; s < 18; ++s)
        Bb[s] = *(const bf16x8*)(wr + ((size_t)s * 64 + lane) * 8);
    for (int u = wv; u < 68; u += 4) {
        int c = u / 17, uu = u - c * 17;
        const ushort_t* gsrc = d2 + ((size_t)(b * 258 + oh0 + c) * 258 + half * 128) * 64;
        stage16(gsrc + (size_t)uu * 512 + ssl(lane, u) * 8, sm + u * 512);
    }
    __syncthreads();

    int rr = wv >> 1, mg = wv & 1;          // output row oh0+rr; mt group mg
    fx4 acc[4];
    #pragma unroll
    for (int i2 = 0; i2 < 4; ++i2) acc[i2] = (fx4){0.f, 0.f, 0.f, 0.f};
    #pragma unroll
    for (int tap = 0; tap < 9; ++tap) {
        int kh = tap / 3, kw = tap % 3;
        int w = rr + 2 - kh;                // window row 0..3
        #pragma unroll
        for (int ks = 0; ks < 2; ++ks) {
            bf16x8 bfr = Bb[tap * 2 + ks];
            #pragma unroll
            for (int mt = 0; mt < 4; ++mt) {
                int px = (2 - kw) + (mg * 4 + mt) * 16 + n16;   // 0..129
                acc[mt] = MFMA16(sld(sm, w * 1088 + px * 8 + ks * 4 + quad), bfr, acc[mt]);
            }
        }
    }
    int co = n16;
    if (co < 3) {
        float bs = bias[co];
        int oh = oh0 + rr;
        #pragma unroll
        for (int mt = 0; mt < 4; ++mt) {
            int ow0 = half * 128 + (mg * 4 + mt) * 16 + quad * 4;
            float4 v;
            v.x = 1.f / (1.f + __expf(-(acc[mt][0] + bs)));
            v.y = 1.f / (1.f + __expf(-(acc[mt][1] + bs)));
            v.z = 1.f / (1.f + __expf(-(acc[mt][2] + bs)));
            v.w = 1.f / (1.f + __expf(-(acc[mt][3] + bs)));
            *(float4*)(out + (((size_t)b * 3 + co) * 256 + oh) * 256 + ow0) = v;
        }
    }
}

// ---------------------------------------------------------------------------
extern "C" void kernel_launch(void* const* d_in, const int* in_sizes, int n_in,
                              void* d_out, int out_size, void* d_ws, size_t ws_size,
                              hipStream_t stream)
{
    const float* x   = (const float*)d_in[0];
    const float* w1  = (const float*)d_in[1];
    const float* b1  = (const float*)d_in[2];
    const float* w2  = (const float*)d_in[3];
    const float* b2  = (const float*)d_in[4];
    const float* w3  = (const float*)d_in[5];
    const float* b3  = (const float*)d_in[6];
    const float* emb = (const float*)d_in[7];
    const float* dw1 = (const float*)d_in[8];
    const float* db1 = (const float*)d_in[9];
    const float* dw2 = (const float*)d_in[10];
    const float* db2 = (const float*)d_in[11];
    const float* dw3 = (const float*)d_in[12];
    const float* db3 = (const float*)d_in[13];
    float* xout = (float*)d_out;

    ushort_t* shared = (ushort_t*)d_ws;
    ushort_t* xp   = shared;                     // 34,611,200
    ushort_t* h2p  = shared + 34611200;          // 17,842,176
    ushort_t* d1c  = shared;                     // 16*130*130*128 = 34,611,200
    ushort_t* d2c  = shared + 34611200;          // 16*258*258*64  = 68,161,536
    ushort_t* x4   = shared + 94252544;          // 8,520,192 (tail of d2c region)
    ushort_t* zb   = shared + 102772736;         // 8,388,608
    ushort_t* qpad = zb + 8388608;               // 8,921,088
    ushort_t* wr1  = qpad + 8921088;             //   4,096
    ushort_t* wr2  = wr1  + 4096;                // 131,072
    ushort_t* wr3  = wr2  + 131072;              //  73,728
    ushort_t* wd1  = wr3  + 73728;               // 131,072
    ushort_t* wd2  = wd1  + 131072;              // 131,072
    ushort_t* wd3  = wd2  + 131072;              //   9,216
    ushort_t* embb = wd3  + 9216;                //  32,768
    float*    se2  = (float*)(embb + 32768);     //     512 f32
    float*    lac  = se2 + 512;

    repack_all<<<2007, 256, 0, stream>>>(w1, w2, w3, dw1, dw2, dw3, emb,
                                         wr1, wr2, wr3, wd1, wd2, wd3,
                                         embb, se2, lac);
    cast_x4 <<<8321, 256, 0, stream>>>(x, x4);
    halo3_k <<<1296, 256, 0, stream>>>(xp, h2p, qpad);

    conv1_mfma<<<4096, 256, 0, stream>>>(x4, wr1, b1, xp);
    conv2_mfma<<<2048, 256, 0, stream>>>(xp, wr2, b2, h2p);
    conv3_mfma<<<2048, 256, 0, stream>>>(h2p, wr3, b3, zb);
    vq_mfma   <<<512,  256, 0, stream>>>(zb, embb, emb, se2, qpad, lac);
    loss_fin_k<<<1, 1, 0, stream>>>(lac, xout + 6291456);

    halo2_k<<<1030, 256, 0, stream>>>(d1c, d2c);

    for (int c0 = 0; c0 < 32; c0 += 16) {
        deconv1_mfma<<<2048, 256, 0, stream>>>(qpad + (size_t)c0 * 278784, wd1, db1, d1c);
        deconv2_mfma<<<4096, 256, 0, stream>>>(d1c, wd2, db2, d2c);
        deconv3_mfma<<<4096, 256, 0, stream>>>(d2c, wd3, db3, xout + (size_t)c0 * 196608);
    }
}

// Round 15
// 526.510 us; speedup vs baseline: 1.0437x; 1.0437x over previous
//
#include <hip/hip_runtime.h>
#include <math.h>

// ---------------------------------------------------------------------------
// VQ-VAE forward, round 14.
// vs round 13 (549us): LDS swizzle corrected. r13's (s>>8) term was wrong —
// deconv2's lane stride is bit 4 (s = C + 16*n16 + quad), so (s>>8) is ~const
// per read (no fix) and flips at 256-slot crossings (added noise to ALL
// kernels, conflicts 4.2e6 -> 7.9e6, non-deconv2 kernels regressed).
// Universal fold: swz(s) = s ^ ((s>>3)&7) ^ ((s>>4)&7). Enumerated: both
// stride-16 (deconv2/conv2/conv3: pos = quad ^ (2n^n)) and stride-8
// (deconv1/vq/deconv3: pos = quad ^ (n ^ n>>1)) patterns are perfectly
// balanced (8 lanes/bank-group = b128 floor). Stage-side involution:
// ssl(lane,u) = lane ^ ((lane>>3)&7) ^ ((4u + (lane>>4))&7).
// Everything else identical to round 13.
// MFMA 16x16x32 layouts (m89): A/B frag row=lane&15, k=(lane>>4)*8+j.
// C/D: col=lane&15, row=(lane>>4)*4+reg.
// ---------------------------------------------------------------------------

typedef __attribute__((ext_vector_type(8))) short bf16x8;
typedef __attribute__((ext_vector_type(4))) float fx4;
typedef unsigned short ushort_t;
#define MFMA16(a, b, c) __builtin_amdgcn_mfma_f32_16x16x32_bf16(a, b, c, 0, 0, 0)

__device__ inline ushort_t f2bf(float f) {
    unsigned u = __float_as_uint(f);
    u += 0x7FFFu + ((u >> 16) & 1u);
    return (ushort_t)(u >> 16);
}
__device__ inline float bf2f(ushort_t h) {
    return __uint_as_float(((unsigned)h) << 16);
}

__device__ __forceinline__ void stage16(const ushort_t* g, ushort_t* l) {
#if __has_builtin(__builtin_amdgcn_global_load_lds)
    __builtin_amdgcn_global_load_lds(
        (const __attribute__((address_space(1))) unsigned int*)g,
        (__attribute__((address_space(3))) unsigned int*)l, 16, 0, 0);
#else
    int lane = threadIdx.x & 63;
    *(int4*)(l + lane * 8) = *(const int4*)g;
#endif
}

// swizzle over 16B slots (involution: only bits 0-2 change, mask from bits 3-6)
__device__ __forceinline__ int swz(int s) {
    return s ^ ((s >> 3) & 7) ^ ((s >> 4) & 7);
}
// stage-side source permutation for chunk u (64 slots), consistent with swz
__device__ __forceinline__ int ssl(int lane, int u) {
    return lane ^ ((lane >> 3) & 7) ^ ((4 * u + (lane >> 4)) & 7);
}
__device__ __forceinline__ bf16x8 sld(const ushort_t* sm, int gslot) {
    return *(const bf16x8*)(sm + (size_t)swz(gslot) * 8);
}

__device__ __forceinline__ void halo_do(
    ushort_t* __restrict__ buf, int B, int H, int W, int C8, int idx)
{
    int perim = 2 * W + 2 * (H - 2);
    int c8 = idx % C8;
    int t = idx / C8;
    int p = t % perim;
    int b = t / perim;
    int r, col;
    if (p < W) { r = 0; col = p; }
    else if (p < 2 * W) { r = H - 1; col = p - W; }
    else { int pp = p - 2 * W; r = 1 + (pp >> 1); col = (pp & 1) ? (W - 1) : 0; }
    size_t off = ((((size_t)b * H + r) * W + col) * C8 + c8) * 8;
    *(int4*)(buf + off) = (int4){0, 0, 0, 0};
}

__global__ __launch_bounds__(256) void halo3_k(
    ushort_t* __restrict__ xp, ushort_t* __restrict__ h2p, ushort_t* __restrict__ qpad)
{
    int i = blockIdx.x * 256 + threadIdx.x;
    if (i < 132096) halo_do(xp, 32, 130, 130, 8, i);
    else if (i < 265216) halo_do(h2p, 32, 66, 66, 16, i - 132096);
    else if (i < 331776) halo_do(qpad, 32, 66, 66, 8, i - 265216);
}
__global__ __launch_bounds__(256) void halo2_k(
    ushort_t* __restrict__ d1c, ushort_t* __restrict__ d2c)
{
    int i = blockIdx.x * 256 + threadIdx.x;
    if (i < 132096) halo_do(d1c, 16, 130, 130, 16, i);
    else if (i < 263680) halo_do(d2c, 16, 258, 258, 8, i - 132096);
}

// x (32,3,256,256) f32 -> x4 [32][258][258][4] bf16 (ci=3 zero); + halo zero
__global__ __launch_bounds__(256) void cast_x4(
    const float* __restrict__ x, ushort_t* __restrict__ x4)
{
    if (blockIdx.x < 8192) {
        int i = blockIdx.x * 256 + threadIdx.x;
        int w = i & 255, h = (i >> 8) & 255, b = i >> 16;
        size_t base = ((size_t)b * 3 * 256 + h) * 256 + w;
        float v0 = x[base];
        float v1 = x[base + 65536];
        float v2 = x[base + 131072];
        uint2 o;
        o.x = (unsigned)f2bf(v0) | ((unsigned)f2bf(v1) << 16);
        o.y = (unsigned)f2bf(v2);
        *(uint2*)(x4 + ((size_t)(b * 258 + h + 1) * 258 + (w + 1)) * 4) = o;
    } else {
        int idx = (blockIdx.x - 8192) * 256 + threadIdx.x;
        if (idx >= 32 * 1032) return;
        int b = idx / 1032;
        int s = idx % 1032;
        int side = s / 258, c = s % 258;
        int r, col;
        if (side == 0) { r = 0; col = c; }
        else if (side == 1) { r = 257; col = c; }
        else if (side == 2) { r = c; col = 0; }
        else { r = c; col = 257; }
        *(uint2*)(x4 + ((size_t)(b * 258 + r) * 258 + col) * 4) = (uint2){0, 0};
    }
}

// ---------------- fused repack: all weights + embb + se2 + lac --------------
// 16-wide swizzled layout: off = ((t*numC + c)*64 + lane)*8 + j ;
// co = t*16 + (lane&15); k = c*32 + (lane>>4)*8 + j
__global__ __launch_bounds__(256) void repack_all(
    const float* __restrict__ w1, const float* __restrict__ w2,
    const float* __restrict__ w3, const float* __restrict__ dw1,
    const float* __restrict__ dw2, const float* __restrict__ dw3,
    const float* __restrict__ emb,
    ushort_t* __restrict__ o1, ushort_t* __restrict__ o2,
    ushort_t* __restrict__ o3, ushort_t* __restrict__ od1,
    ushort_t* __restrict__ od2, ushort_t* __restrict__ od3,
    ushort_t* __restrict__ embb, float* __restrict__ se2,
    float* __restrict__ lac)
{
    int gi = blockIdx.x * 256 + threadIdx.x;
    if (gi < 4096) {                         // w1 [64co][3ci][4][4]
        int i = gi;
        int j = i & 7, lane = (i >> 3) & 63, tc = i >> 9;
        int c = tc & 1, t = tc >> 1;
        int co = t * 16 + (lane & 15);
        int k = c * 32 + (lane >> 4) * 8 + j;
        int kh = k >> 4, kw = (k >> 2) & 3, ci = k & 3;
        o1[i] = (ci < 3) ? f2bf(w1[((co * 3 + ci) * 4 + kh) * 4 + kw]) : (ushort_t)0;
    } else if (gi < 135168) {                // w2 [128co][64ci][4][4], numC=32
        int i = gi - 4096;
        int j = i & 7, lane = (i >> 3) & 63, tc = i >> 9;
        int c = tc & 31, t = tc >> 5;
        int co = t * 16 + (lane & 15);
        int k = c * 32 + (lane >> 4) * 8 + j;
        int tap = k >> 6, ci = k & 63, kh = tap >> 2, kw = tap & 3;
        o2[i] = f2bf(w2[((co * 64 + ci) * 4 + kh) * 4 + kw]);
    } else if (gi < 208896) {                // w3 [64co][128ci][3][3], numC=36
        int i = gi - 135168;
        int j = i & 7, lane = (i >> 3) & 63, tc = i >> 9;
        int c = tc % 36, t = tc / 36;
        int co = t * 16 + (lane & 15);
        int k = c * 32 + (lane >> 4) * 8 + j;
        int tap = k >> 7, ci = k & 127, kh = tap / 3, kw = tap % 3;
        o3[i] = f2bf(w3[((co * 128 + ci) * 3 + kh) * 3 + kw]);
    } else if (gi < 339968) {                // dw1 [64ci][128co][4][4], numC=32
        int i = gi - 208896;
        int j = i & 7, lane = (i >> 3) & 63, tc = i >> 9;
        int c = tc & 31, t = tc >> 5;
        int co = t * 16 + (lane & 15);
        int k = c * 32 + (lane >> 4) * 8 + j;
        int tap = k >> 6, ci = k & 63, kh = tap >> 2, kw = tap & 3;
        od1[i] = f2bf(dw1[((ci * 128 + co) * 4 + kh) * 4 + kw]);
    } else if (gi < 471040) {                // dw2 [128ci][64co][4][4], numC=64
        int i = gi - 339968;
        int j = i & 7, lane = (i >> 3) & 63, tc = i >> 9;
        int c = tc & 63, t = tc >> 6;
        int co = t * 16 + (lane & 15);
        int k = c * 32 + (lane >> 4) * 8 + j;
        int tap = k >> 7, ci = k & 127, kh = tap >> 2, kw = tap & 3;
        od2[i] = f2bf(dw2[((ci * 64 + co) * 4 + kh) * 4 + kw]);
    } else if (gi < 480256) {                // dw3 [64ci][3co][3][3], numC=18
        int i = gi - 471040;
        int j = i & 7, lane = (i >> 3) & 63, c = i >> 9;
        int co = lane & 15;
        int k = c * 32 + (lane >> 4) * 8 + j;
        int tap = k >> 6, ci = k & 63, kh = tap / 3, kw = tap % 3;
        od3[i] = (co < 3) ? f2bf(dw3[((ci * 3 + co) * 3 + kh) * 3 + kw]) : (ushort_t)0;
    } else if (gi < 513024) {                // embb [512n][64k] B-frag layout
        int i = gi - 480256;
        int j = i & 7, lane = (i >> 3) & 63, c = (i >> 9) & 1, nt = i >> 10;
        int n = nt * 16 + (lane & 15);
        int k = c * 32 + (lane >> 4) * 8 + j;
        embb[i] = f2bf(emb[n * 64 + k]);
    } else if (gi < 513536) {                // se2[512] fp32 |e|^2
        int n = gi - 513024;
        const float* e = emb + n * 64;
        float s = 0.f;
        for (int d = 0; d < 64; ++d) s = fmaf(e[d], e[d], s);
        se2[n] = s;
    } else if (gi == 513536) {
        lac[0] = 0.f;
    }
}

// ------------------------- conv1 MFMA ---------------------------------------
// grid 4096 = 8 xcd x (32 b x 16 ohi); oh = xcd*16 + ohi
__global__ __launch_bounds__(256) void conv1_mfma(
    const ushort_t* __restrict__ x4, const ushort_t* __restrict__ wr,
    const float* __restrict__ bias, ushort_t* __restrict__ xp)
{
    __shared__ ushort_t sm[4608];
    int tid = threadIdx.x;
    int wv = tid >> 6, lane = tid & 63;
    int n16 = lane & 15, quad = lane >> 4;
    int i = blockIdx.x;
    int xcd = i & 7, j = i >> 3;
    int b = j >> 4, oh = xcd * 16 + (j & 15);
    const ushort_t* gsrc = x4 + (size_t)(b * 258 + 2 * oh) * 1032;
    bf16x8 bfr[4][2];
    #pragma unroll
    for (int nt = 0; nt < 4; ++nt)
        #pragma unroll
        for (int c = 0; c < 2; ++c)
            bfr[nt][c] = *(const bf16x8*)(wr + ((size_t)(nt * 2 + c) * 64 + lane) * 8);
    for (int u = wv; u < 9; u += 4)
        stage16(gsrc + u * 512 + ssl(lane, u) * 8, sm + u * 512);
    __syncthreads();

    fx4 acc[2][4];
    #pragma unroll
    for (int i2 = 0; i2 < 2; ++i2)
        #pragma unroll
        for (int j2 = 0; j2 < 4; ++j2) acc[i2][j2] = (fx4){0.f, 0.f, 0.f, 0.f};
    #pragma unroll
    for (int c = 0; c < 2; ++c) {
        int kh = 2 * c + (quad >> 1);
        int kwh = quad & 1;
        bf16x8 af[2];
        #pragma unroll
        for (int mt = 0; mt < 2; ++mt) {
            int ow = (wv * 2 + mt) * 16 + n16;
            af[mt] = sld(sm, kh * 129 + ow + kwh);
        }
        #pragma unroll
        for (int mt = 0; mt < 2; ++mt)
            #pragma unroll
            for (int nt = 0; nt < 4; ++nt)
                acc[mt][nt] = MFMA16(af[mt], bfr[nt][c], acc[mt][nt]);
    }
    #pragma unroll
    for (int nt = 0; nt < 4; ++nt) {
        int co = nt * 16 + n16;
        float bs = bias[co];
        #pragma unroll
        for (int mt = 0; mt < 2; ++mt) {
            #pragma unroll
            for (int r = 0; r < 4; ++r) {
                int ow = (wv * 2 + mt) * 16 + quad * 4 + r;
                xp[((size_t)(b * 130 + oh + 1) * 130 + (ow + 1)) * 64 + co] =
                    f2bf(fmaxf(acc[mt][nt][r] + bs, 0.f));
            }
        }
    }
}

// ------------------------- conv2 MFMA ---------------------------------------
// grid 2048 = 8 xcd x (32 b x 8 ohi); oh = xcd*8 + ohi
__global__ __launch_bounds__(256, 2) void conv2_mfma(
    const ushort_t* __restrict__ xp, const ushort_t* __restrict__ wr,
    const float* __restrict__ bias, ushort_t* __restrict__ h2p)
{
    __shared__ ushort_t sm[33280];
    int tid = threadIdx.x;
    int wv = tid >> 6, lane = tid & 63;
    int n16 = lane & 15, quad = lane >> 4;
    int i = blockIdx.x;
    int xcd = i & 7, j = i >> 3;
    int b = j >> 3, oh = xcd * 8 + (j & 7);
    const ushort_t* gsrc = xp + (size_t)(b * 130 + 2 * oh) * 130 * 64;
    int mg = wv & 1, ng = wv >> 1;

    bf16x8 Bb[8];
    #pragma unroll
    for (int nt = 0; nt < 4; ++nt)
        #pragma unroll
        for (int ks = 0; ks < 2; ++ks)
            Bb[nt * 2 + ks] = *(const bf16x8*)(
                wr + ((size_t)((ng * 4 + nt) * 32 + 0 * 2 + ks) * 64 + lane) * 8);
    for (int u = wv; u < 65; u += 4)
        stage16(gsrc + (size_t)u * 512 + ssl(lane, u) * 8, sm + u * 512);
    __syncthreads();

    fx4 acc[2][4];
    #pragma unroll
    for (int i2 = 0; i2 < 2; ++i2)
        #pragma unroll
        for (int j2 = 0; j2 < 4; ++j2) acc[i2][j2] = (fx4){0.f, 0.f, 0.f, 0.f};
    for (int tap = 0; tap < 16; ++tap) {
        if (tap > 0) {
            #pragma unroll
            for (int nt = 0; nt < 4; ++nt)
                #pragma unroll
                for (int ks = 0; ks < 2; ++ks)
                    Bb[nt * 2 + ks] = *(const bf16x8*)(
                        wr + ((size_t)((ng * 4 + nt) * 32 + tap * 2 + ks) * 64 + lane) * 8);
        }
        int kh = tap >> 2, kw = tap & 3;
        #pragma unroll
        for (int ks = 0; ks < 2; ++ks) {
            bf16x8 af[2];
            #pragma unroll
            for (int mt = 0; mt < 2; ++mt) {
                int px = kw + 2 * ((mg * 2 + mt) * 16 + n16);   // 0..129
                af[mt] = sld(sm, (kh * 130 + px) * 8 + ks * 4 + quad);
            }
            #pragma unroll
            for (int mt = 0; mt < 2; ++mt)
                #pragma unroll
                for (int nt = 0; nt < 4; ++nt)
                    acc[mt][nt] = MFMA16(af[mt], Bb[nt * 2 + ks], acc[mt][nt]);
        }
    }
    #pragma unroll
    for (int nt = 0; nt < 4; ++nt) {
        int co = (ng * 4 + nt) * 16 + n16;
        float bs = bias[co];
        #pragma unroll
        for (int mt = 0; mt < 2; ++mt) {
            #pragma unroll
            for (int r = 0; r < 4; ++r) {
                int ow = (mg * 2 + mt) * 16 + quad * 4 + r;
                h2p[((size_t)(b * 66 + oh + 1) * 66 + (ow + 1)) * 128 + co] =
                    f2bf(fmaxf(acc[mt][nt][r] + bs, 0.f));
            }
        }
    }
}

// ------------------------- conv3 MFMA ---------------------------------------
// grid 2048 = 8 xcd x (32 b x 8 ohi); oh = xcd*8 + ohi
__global__ __launch_bounds__(256, 2) void conv3_mfma(
    const ushort_t* __restrict__ hp, const ushort_t* __restrict__ wr,
    const float* __restrict__ bias, ushort_t* __restrict__ z)
{
    __shared__ ushort_t sm[25600];
    int tid = threadIdx.x;
    int wv = tid >> 6, lane = tid & 63;
    int n16 = lane & 15, quad = lane >> 4;
    int i = blockIdx.x;
    int xcd = i & 7, j = i >> 3;
    int b = j >> 3, oh = xcd * 8 + (j & 7);
    const ushort_t* gsrc = hp + (size_t)(b * 66 + oh) * 66 * 128;
    const ushort_t* wb = wr + ((size_t)wv * 36 * 64 + lane) * 8;
    bf16x8 Bb[36];
    #pragma unroll
    for (int s = 0; s < 36; ++s)
        Bb[s] = *(const bf16x8*)(wb + (size_t)s * 512);
    for (int u = wv; u < 50; u += 4)
        stage16(gsrc + (size_t)u * 512 + ssl(lane, u) * 8, sm + u * 512);
    __syncthreads();

    fx4 acc[4];
    #pragma unroll
    for (int i2 = 0; i2 < 4; ++i2) acc[i2] = (fx4){0.f, 0.f, 0.f, 0.f};
    #pragma unroll
    for (int tap = 0; tap < 9; ++tap) {
        int kh = tap / 3, kw = tap % 3;
        #pragma unroll
        for (int ks = 0; ks < 4; ++ks) {
            bf16x8 af[4];
            #pragma unroll
            for (int mt = 0; mt < 4; ++mt) {
                int px = kw + mt * 16 + n16;                    // 0..65
                af[mt] = sld(sm, (kh * 66 + px) * 16 + ks * 4 + quad);
            }
            #pragma unroll
            for (int mt = 0; mt < 4; ++mt)
                acc[mt] = MFMA16(af[mt], Bb[tap * 4 + ks], acc[mt]);
        }
    }
    int co = wv * 16 + n16;
    float bs = bias[co];
    #pragma unroll
    for (int mt = 0; mt < 4; ++mt) {
        #pragma unroll
        for (int r = 0; r < 4; ++r) {
            int ow = mt * 16 + quad * 4 + r;
            z[((size_t)(b * 64 + oh) * 64 + ow) * 64 + co] =
                f2bf(fmaxf(acc[mt][r] + bs, 0.f));
        }
    }
}

// ------------------------- VQ MFMA ------------------------------------------
__global__ __launch_bounds__(256) void vq_mfma(
    const ushort_t* __restrict__ z, const ushort_t* __restrict__ embb,
    const float* __restrict__ emb, const float* __restrict__ se2g,
    ushort_t* __restrict__ qpad, float* __restrict__ loss_acc)
{
    __shared__ ushort_t smz[16384];
    __shared__ float sse2[512];
    __shared__ float red[256];
    int tid = threadIdx.x;
    int wv = tid >> 6, lane = tid & 63;
    int n16 = lane & 15, quad = lane >> 4;
    int blk = blockIdx.x;                   // 512
    const ushort_t* gsrc = z + (size_t)blk * 16384;
    for (int u = wv; u < 32; u += 4)
        stage16(gsrc + (size_t)u * 512 + ssl(lane, u) * 8, smz + u * 512);
    for (int i = tid; i < 512; i += 256) sse2[i] = se2g[i];
    __syncthreads();

    bf16x8 a[4][2];
    #pragma unroll
    for (int mt = 0; mt < 4; ++mt)
        #pragma unroll
        for (int ks = 0; ks < 2; ++ks)
            a[mt][ks] = sld(smz, (wv * 64 + mt * 16 + n16) * 8 + ks * 4 + quad);

    float best[4][4];
    int bid[4][4];
    #pragma unroll
    for (int mt = 0; mt < 4; ++mt)
        #pragma unroll
        for (int r = 0; r < 4; ++r) { best[mt][r] = 1e30f; bid[mt][r] = 0; }

    for (int nt = 0; nt < 32; ++nt) {
        bf16x8 b0 = *(const bf16x8*)(embb + ((size_t)(nt * 2 + 0) * 64 + lane) * 8);
        bf16x8 b1 = *(const bf16x8*)(embb + ((size_t)(nt * 2 + 1) * 64 + lane) * 8);
        float s2 = sse2[nt * 16 + n16];
        int myn = nt * 16 + n16;
        #pragma unroll
        for (int mt = 0; mt < 4; ++mt) {
            fx4 acc = (fx4){0.f, 0.f, 0.f, 0.f};
            acc = MFMA16(a[mt][0], b0, acc);
            acc = MFMA16(a[mt][1], b1, acc);
            #pragma unroll
            for (int r = 0; r < 4; ++r) {
                float sc = fmaf(-2.f, acc[r], s2);
                if (sc < best[mt][r]) { best[mt][r] = sc; bid[mt][r] = myn; }
            }
        }
    }

    float lsum = 0.f;
    #pragma unroll
    for (int mt = 0; mt < 4; ++mt) {
        #pragma unroll
        for (int r = 0; r < 4; ++r) {
            float bs = best[mt][r];
            int bi = bid[mt][r];
            #pragma unroll
            for (int st = 1; st < 16; st <<= 1) {
                float os = __shfl_xor(bs, st, 64);
                int oi = __shfl_xor(bi, st, 64);
                if (os < bs || (os == bs && oi < bi)) { bs = os; bi = oi; }
            }
            int ml = wv * 64 + mt * 16 + quad * 4 + r;
            int pos = blk * 256 + ml;
            int b = pos >> 12, h = (pos >> 6) & 63, w = pos & 63;
            float4 ev = *(const float4*)(emb + (size_t)bi * 64 + n16 * 4);
            int slot = ml * 8 + (n16 >> 1);
            const ushort_t* zp = smz + (size_t)swz(slot) * 8 + (n16 & 1) * 4;
            float d0 = ev.x - bf2f(zp[0]);
            float d1 = ev.y - bf2f(zp[1]);
            float d2 = ev.z - bf2f(zp[2]);
            float d3 = ev.w - bf2f(zp[3]);
            lsum = fmaf(d0, d0, lsum);
            lsum = fmaf(d1, d1, lsum);
            lsum = fmaf(d2, d2, lsum);
            lsum = fmaf(d3, d3, lsum);
            uint2 o;
            o.x = (unsigned)f2bf(ev.x) | ((unsigned)f2bf(ev.y) << 16);
            o.y = (unsigned)f2bf(ev.z) | ((unsigned)f2bf(ev.w) << 16);
            *(uint2*)(qpad + ((size_t)(b * 66 + h + 1) * 66 + (w + 1)) * 64 + n16 * 4) = o;
        }
    }
    red[tid] = lsum;
    __syncthreads();
    for (int s = 128; s > 0; s >>= 1) {
        if (tid < s) red[tid] += red[tid + s];
        __syncthreads();
    }
    if (tid == 0) atomicAdd(loss_acc, red[0]);
}

__global__ void loss_fin_k(const float* __restrict__ acc, float* __restrict__ out)
{
    out[0] = 1.25f * acc[0] / 8388608.0f;
}

// ------------------------- deconv1 MFMA -------------------------------------
// grid 2048 = 8 xcd x (16 b x 16 ohi); oh = xcd*16 + ohi
__global__ __launch_bounds__(256, 2) void deconv1_mfma(
    const ushort_t* __restrict__ q, const ushort_t* __restrict__ wr,
    const float* __restrict__ bias, ushort_t* __restrict__ d1)
{
    __shared__ ushort_t sm[8704];
    int tid = threadIdx.x;
    int wv = tid >> 6, lane = tid & 63;
    int n16 = lane & 15, quad = lane >> 4;
    int i = blockIdx.x;
    int xcd = i & 7, j = i >> 3;
    int b = j >> 4, oh = xcd * 16 + (j & 15);
    int h0 = (oh + 1) & 1;
    int ihp0 = ((oh + 1 - h0) >> 1) + 1;
    const ushort_t* gsrc = q + (size_t)(b * 66 + ihp0 - 1) * 66 * 64;
    int pw = wv & 1, ng = wv >> 1;
    int q0 = 1 - pw;
    bf16x8 Bb[4][8];
    #pragma unroll
    for (int nt = 0; nt < 4; ++nt) {
        const ushort_t* wb = wr + ((size_t)(ng * 4 + nt) * 32 * 64 + lane) * 8;
        #pragma unroll
        for (int t2 = 0; t2 < 2; ++t2)
            #pragma unroll
            for (int t3 = 0; t3 < 2; ++t3)
                #pragma unroll
                for (int ks = 0; ks < 2; ++ks) {
                    int tap = (h0 + 2 * t2) * 4 + (q0 + 2 * t3);
                    Bb[nt][t2 * 4 + t3 * 2 + ks] =
                        *(const bf16x8*)(wb + (size_t)(tap * 2 + ks) * 512);
                }
    }
    for (int u = wv; u < 17; u += 4)
        stage16(gsrc + (size_t)u * 512 + ssl(lane, u) * 8, sm + u * 512);
    __syncthreads();

    fx4 acc[4][4];
    #pragma unroll
    for (int i2 = 0; i2 < 4; ++i2)
        #pragma unroll
        for (int j2 = 0; j2 < 4; ++j2) acc[i2][j2] = (fx4){0.f, 0.f, 0.f, 0.f};
    #pragma unroll
    for (int t2 = 0; t2 < 2; ++t2) {
        int lrow = 1 - t2;
        #pragma unroll
        for (int t3 = 0; t3 < 2; ++t3) {
            int cadd = pw + (t3 == 0 ? 1 : 0);
            #pragma unroll
            for (int ks = 0; ks < 2; ++ks) {
                bf16x8 af[4];
                #pragma unroll
                for (int mt = 0; mt < 4; ++mt) {
                    int px = cadd + mt * 16 + n16;              // 0..65
                    af[mt] = sld(sm, (lrow * 66 + px) * 8 + ks * 4 + quad);
                }
                #pragma unroll
                for (int mt = 0; mt < 4; ++mt)
                    #pragma unroll
                    for (int nt = 0; nt < 4; ++nt)
                        acc[mt][nt] = MFMA16(af[mt], Bb[nt][t2 * 4 + t3 * 2 + ks], acc[mt][nt]);
            }
        }
    }
    #pragma unroll
    for (int nt = 0; nt < 4; ++nt) {
        int co = (ng * 4 + nt) * 16 + n16;
        float bs = bias[co];
        #pragma unroll
        for (int mt = 0; mt < 4; ++mt) {
            #pragma unroll
            for (int r = 0; r < 4; ++r) {
                int ow = 2 * (mt * 16 + quad * 4 + r) + pw;
                d1[((size_t)(b * 130 + oh + 1) * 130 + (ow + 1)) * 128 + co] =
                    f2bf(fmaxf(acc[mt][nt][r] + bs, 0.f));
            }
        }
    }
}

// ------------------------- deconv2 MFMA (full-row, 4mt x 4nt) ---------------
// grid 4096 = 8 xcd x (16 b x 32 ohi); oh = xcd*32 + ohi
__global__ __launch_bounds__(256, 2) void deconv2_mfma(
    const ushort_t* __restrict__ d1, const ushort_t* __restrict__ wr,
    const float* __restrict__ bias, ushort_t* __restrict__ d2)
{
    __shared__ ushort_t sm[33280];
    int tid = threadIdx.x;
    int wv = tid >> 6, lane = tid & 63;
    int n16 = lane & 15, quad = lane >> 4;
    int i = blockIdx.x;
    int xcd = i & 7, j = i >> 3;
    int b = j >> 5, oh = xcd * 32 + (j & 31);
    int h0 = (oh + 1) & 1;
    int ihp0 = ((oh + 1 - h0) >> 1) + 1;    // 1..129
    const ushort_t* gsrc = d1 + (size_t)(b * 130 + ihp0 - 1) * 130 * 128;
    int pw = wv & 1, mh = wv >> 1;
    int q0 = 1 - pw;

    int taps[4];
    #pragma unroll
    for (int g = 0; g < 4; ++g)
        taps[g] = (h0 + 2 * (g >> 1)) * 4 + (q0 + 2 * (g & 1));

    bf16x8 Bb[16];
    #pragma unroll
    for (int nt = 0; nt < 4; ++nt)
        #pragma unroll
        for (int ks = 0; ks < 4; ++ks)
            Bb[nt * 4 + ks] = *(const bf16x8*)(
                wr + ((size_t)(nt * 64 + taps[0] * 4 + ks) * 64 + lane) * 8);

    for (int u = wv; u < 65; u += 4)
        stage16(gsrc + (size_t)u * 512 + ssl(lane, u) * 8, sm + u * 512);
    __syncthreads();

    fx4 acc[4][4];
    #pragma unroll
    for (int i2 = 0; i2 < 4; ++i2)
        #pragma unroll
        for (int j2 = 0; j2 < 4; ++j2) acc[i2][j2] = (fx4){0.f, 0.f, 0.f, 0.f};

    #pragma unroll
    for (int g = 0; g < 4; ++g) {
        if (g > 0) {
            int tapc = taps[g];
            #pragma unroll
            for (int nt = 0; nt < 4; ++nt)
                #pragma unroll
                for (int ks = 0; ks < 4; ++ks)
                    Bb[nt * 4 + ks] = *(const bf16x8*)(
                        wr + ((size_t)(nt * 64 + tapc * 4 + ks) * 64 + lane) * 8);
        }
        int t2 = g >> 1, t3 = g & 1;
        int lrow = 1 - t2;
        int cadd = pw + (t3 == 0 ? 1 : 0);
        #pragma unroll
        for (int ks = 0; ks < 4; ++ks) {
            bf16x8 af[4];
            #pragma unroll
            for (int mt = 0; mt < 4; ++mt) {
                int px = cadd + (mh * 4 + mt) * 16 + n16;       // 0..129
                af[mt] = sld(sm, (lrow * 130 + px) * 16 + ks * 4 + quad);
            }
            #pragma unroll
            for (int mt = 0; mt < 4; ++mt)
                #pragma unroll
                for (int nt = 0; nt < 4; ++nt)
                    acc[mt][nt] = MFMA16(af[mt], Bb[nt * 4 + ks], acc[mt][nt]);
        }
    }

    #pragma unroll
    for (int nt = 0; nt < 4; ++nt) {
        int co = nt * 16 + n16;
        float bs = bias[co];
        #pragma unroll
        for (int mt = 0; mt < 4; ++mt) {
            #pragma unroll
            for (int r = 0; r < 4; ++r) {
                int t = (mh * 4 + mt) * 16 + quad * 4 + r;      // 0..127
                int ow = 2 * t + pw;
                d2[((size_t)(b * 258 + oh + 1) * 258 + (ow + 1)) * 64 + co] =
                    f2bf(fmaxf(acc[mt][nt][r] + bs, 0.f));
            }
        }
    }
}

// ------------------------- deconv3 MFMA (2 rows/block) ----------------------
// grid 4096 = 8 xcd x (16 b x 2 half x 16 ohpi); oh0 = (xcd*16+ohpi)*2.
__global__ __launch_bounds__(256, 4) void deconv3_mfma(
    const ushort_t* __restrict__ d2, const ushort_t* __restrict__ wr,
    const float* __restrict__ bias, float* __restrict__ out)
{
    __shared__ ushort_t sm[34816];
    int tid = threadIdx.x;
    int wv = tid >> 6, lane = tid & 63;
    int n16 = lane & 15, quad = lane >> 4;
    int i = blockIdx.x;
    int xcd = i & 7, j = i >> 3;            // j 0..511
    int bh = j >> 4;                        // 0..31
    int b = bh >> 1, half = bh & 1;
    int oh0 = (xcd * 16 + (j & 15)) * 2;    // 0,2,..,254
    bf16x8 Bb[18];
    #pragma unroll
    for (int s = 0; s < 18; ++s)
        Bb[s] = *(const bf16x8*)(wr + ((size_t)s * 64 + lane) * 8);
    for (int u = wv; u < 68; u += 4) {
        int c = u / 17, uu = u - c * 17;
        const ushort_t* gsrc = d2 + ((size_t)(b * 258 + oh0 + c) * 258 + half * 128) * 64;
        stage16(gsrc + (size_t)uu * 512 + ssl(lane, u) * 8, sm + u * 512);
    }
    __syncthreads();

    int rr = wv >> 1, mg = wv & 1;
    fx4 acc[4];
    #pragma unroll
    for (int i2 = 0; i2 < 4; ++i2) acc[i2] = (fx4){0.f, 0.f, 0.f, 0.f};
    #pragma unroll
    for (int tap = 0; tap < 9; ++tap) {
        int kh = tap / 3, kw = tap % 3;
        int w = rr + 2 - kh;                // window row 0..3
        #pragma unroll
        for (int ks = 0; ks < 2; ++ks) {
            bf16x8 bfr = Bb[tap * 2 + ks];
            #pragma unroll
            for (int mt = 0; mt < 4; ++mt) {
                int px = (2 - kw) + (mg * 4 + mt) * 16 + n16;   // 0..129
                acc[mt] = MFMA16(sld(sm, w * 1088 + px * 8 + ks * 4 + quad), bfr, acc[mt]);
            }
        }
    }
    int co = n16;
    if (co < 3) {
        float bs = bias[co];
        int oh = oh0 + rr;
        #pragma unroll
        for (int mt = 0; mt < 4; ++mt) {
            int ow0 = half * 128 + (mg * 4 + mt) * 16 + quad * 4;
            float4 v;
            v.x = 1.f / (1.f + __expf(-(acc[mt][0] + bs)));
            v.y = 1.f / (1.f + __expf(-(acc[mt][1] + bs)));
            v.z = 1.f / (1.f + __expf(-(acc[mt][2] + bs)));
            v.w = 1.f / (1.f + __expf(-(acc[mt][3] + bs)));
            *(float4*)(out + (((size_t)b * 3 + co) * 256 + oh) * 256 + ow0) = v;
        }
    }
}

// ---------------------------------------------------------------------------
extern "C" void kernel_launch(void* const* d_in, const int* in_sizes, int n_in,
                              void* d_out, int out_size, void* d_ws, size_t ws_size,
                              hipStream_t stream)
{
    const float* x   = (const float*)d_in[0];
    const float* w1  = (const float*)d_in[1];
    const float* b1  = (const float*)d_in[2];
    const float* w2  = (const float*)d_in[3];
    const float* b2  = (const float*)d_in[4];
    const float* w3  = (const float*)d_in[5];
    const float* b3  = (const float*)d_in[6];
    const float* emb = (const float*)d_in[7];
    const float* dw1 = (const float*)d_in[8];
    const float* db1 = (const float*)d_in[9];
    const float* dw2 = (const float*)d_in[10];
    const float* db2 = (const float*)d_in[11];
    const float* dw3 = (const float*)d_in[12];
    const float* db3 = (const float*)d_in[13];
    float* xout = (float*)d_out;

    ushort_t* shared = (ushort_t*)d_ws;
    ushort_t* xp   = shared;                     // 34,611,200
    ushort_t* h2p  = shared + 34611200;          // 17,842,176
    ushort_t* d1c  = shared;                     // 16*130*130*128 = 34,611,200
    ushort_t* d2c  = shared + 34611200;          // 16*258*258*64  = 68,161,536
    ushort_t* x4   = shared + 94252544;          // 8,520,192 (tail of d2c region)
    ushort_t* zb   = shared + 102772736;         // 8,388,608
    ushort_t* qpad = zb + 8388608;               // 8,921,088
    ushort_t* wr1  = qpad + 8921088;             //   4,096
    ushort_t* wr2  = wr1  + 4096;                // 131,072
    ushort_t* wr3  = wr2  + 131072;              //  73,728
    ushort_t* wd1  = wr3  + 73728;               // 131,072
    ushort_t* wd2  = wd1  + 131072;              // 131,072
    ushort_t* wd3  = wd2  + 131072;              //   9,216
    ushort_t* embb = wd3  + 9216;                //  32,768
    float*    se2  = (float*)(embb + 32768);     //     512 f32
    float*    lac  = se2 + 512;

    repack_all<<<2007, 256, 0, stream>>>(w1, w2, w3, dw1, dw2, dw3, emb,
                                         wr1, wr2, wr3, wd1, wd2, wd3,
                                         embb, se2, lac);
    cast_x4 <<<8321, 256, 0, stream>>>(x, x4);
    halo3_k <<<1296, 256, 0, stream>>>(xp, h2p, qpad);

    conv1_mfma<<<4096, 256, 0, stream>>>(x4, wr1, b1, xp);
    conv2_mfma<<<2048, 256, 0, stream>>>(xp, wr2, b2, h2p);
    conv3_mfma<<<2048, 256, 0, stream>>>(h2p, wr3, b3, zb);
    vq_mfma   <<<512,  256, 0, stream>>>(zb, embb, emb, se2, qpad, lac);
    loss_fin_k<<<1, 1, 0, stream>>>(lac, xout + 6291456);

    halo2_k<<<1030, 256, 0, stream>>>(d1c, d2c);

    for (int c0 = 0; c0 < 32; c0 += 16) {
        deconv1_mfma<<<2048, 256, 0, stream>>>(qpad + (size_t)c0 * 278784, wd1, db1, d1c);
        deconv2_mfma<<<4096, 256, 0, stream>>>(d1c, wd2, db2, d2c);
        deconv3_mfma<<<4096, 256, 0, stream>>>(d2c, wd3, db3, xout + (size_t)c0 * 196608);
    }
}